// Round 4
// baseline (28132.846 us; speedup 1.0000x reference)
//
#include <hip/hip_runtime.h>
#include <math.h>

// Problem constants
#define HH   300
#define H3   900
#define MMOL 256
#define LATM 128
#define AA   32769        // 1 + 256*128
#define NBB  6
#define BBND 131073       // 1 + 4*256*128
#define AFD  133
#define BFD  147
#define MLR  (MMOL * LATM)   // 32768

static __device__ __forceinline__ float sigm(float x) { return 1.0f / (1.0f + expf(-x)); }

// ---------------------------------------------------------------------------
// Tiled fp32 GEMM: C[rows,N] = act( X[rows,K] @ Wrow(n)=W[n*ldw .. n*ldw+K) (+Bias) (+=C) )
// ---------------------------------------------------------------------------
template<bool RELU, bool BIAS, bool ACCUM>
__global__ __launch_bounds__(256)
void gemm_nt(const float* __restrict__ X, const float* __restrict__ W, int ldw,
             const float* __restrict__ Bias, float* __restrict__ C,
             int rows, int N, int K)
{
    const int BM = 64, BN = 64, BK = 16;
    __shared__ float Xs[BK][BM + 1];
    __shared__ float Ws[BK][BN + 1];

    int row0 = blockIdx.x * BM;
    int col0 = blockIdx.y * BN;
    int tid  = threadIdx.x;
    int tm0  = (tid >> 4) * 4;
    int tn0  = (tid & 15) * 4;

    float acc[4][4] = {};

    for (int k0 = 0; k0 < K; k0 += BK) {
#pragma unroll
        for (int l = 0; l < 4; ++l) {
            int idx = tid + l * 256;
            int m   = idx >> 4;
            int k   = idx & 15;
            int gk  = k0 + k;
            float v = 0.0f;
            int gr = row0 + m;
            if (gr < rows && gk < K) v = X[(long)gr * K + gk];
            Xs[k][m] = v;
            float w = 0.0f;
            int gc = col0 + m;
            if (gc < N && gk < K) w = W[(long)gc * ldw + gk];
            Ws[k][m] = w;
        }
        __syncthreads();
#pragma unroll
        for (int kk = 0; kk < BK; ++kk) {
            float xr[4], wr[4];
#pragma unroll
            for (int i = 0; i < 4; ++i) xr[i] = Xs[kk][tm0 + i];
#pragma unroll
            for (int j = 0; j < 4; ++j) wr[j] = Ws[kk][tn0 + j];
#pragma unroll
            for (int i = 0; i < 4; ++i)
#pragma unroll
                for (int j = 0; j < 4; ++j)
                    acc[i][j] += xr[i] * wr[j];
        }
        __syncthreads();
    }

#pragma unroll
    for (int i = 0; i < 4; ++i) {
        int gr = row0 + tm0 + i;
        if (gr >= rows) continue;
#pragma unroll
        for (int j = 0; j < 4; ++j) {
            int gc = col0 + tn0 + j;
            if (gc >= N) continue;
            float v = acc[i][j];
            if (BIAS)  v += Bias[gc];
            if (ACCUM) v += C[(long)gr * N + gc];
            if (RELU)  v = fmaxf(v, 0.0f);
            C[(long)gr * N + gc] = v;
        }
    }
}

// ---------------------------------------------------------------------------
// In-place row-ownership GEMM: P[r, 0:150) = (P[r, 0:300) @ W[150:300, :]^T)
// Each block owns 16 full rows: stages them to LDS, computes, epilogue-writes
// only its own rows -> in-place safe. W read from global (L2-resident).
// ---------------------------------------------------------------------------
__global__ __launch_bounds__(256)
void vw_hi_inplace(float* __restrict__ P, const float* __restrict__ W, int rows)
{
    __shared__ float Xs[16][301];
    int r0  = blockIdx.x * 16;
    int tid = threadIdx.x;
    for (int i = tid; i < 16 * 300; i += 256) {
        int r = i / 300, c = i - r * 300;
        int gr = r0 + r;
        Xs[r][c] = (gr < rows) ? P[(long)gr * 300 + c] : 0.0f;
    }
    __syncthreads();

    int r  = tid >> 4;     // 0..15
    int cg = tid & 15;     // 0..15
    float acc[10];
#pragma unroll
    for (int u = 0; u < 10; ++u) acc[u] = 0.0f;

    for (int k = 0; k < 300; ++k) {
        float xv = Xs[r][k];
#pragma unroll
        for (int u = 0; u < 10; ++u) {
            int j = cg + 16 * u;
            if (j < 150) acc[u] += xv * W[(long)(150 + j) * 300 + k];
        }
    }
    int gr = r0 + r;
    if (gr < rows) {
#pragma unroll
        for (int u = 0; u < 10; ++u) {
            int j = cg + 16 * u;
            if (j < 150) P[(long)gr * 300 + j] = acc[u];
        }
    }
}

// ---------------------------------------------------------------------------
// Half-column bond update:
//  P[b, c0+cn] = relu( relu(FB[b]@WiB[c0+cn]^T) + Th[b2a[b],cn] - Vsrc[b2revb[b]*vstride+cn] )
// cn in [0,150). K = 147 (input_bond recomputed; never stored).
// ---------------------------------------------------------------------------
__global__ __launch_bounds__(256)
void bond_half(const float* __restrict__ FB, const float* __restrict__ WiB,
               const float* __restrict__ Th, const float* __restrict__ Vsrc, int vstride,
               const int* __restrict__ b2a, const int* __restrict__ b2revb,
               float* __restrict__ P, int c0, int rows)
{
    const int BM = 64, BN = 64, BK = 16;
    __shared__ float Xs[BK][BM + 1];
    __shared__ float Ws[BK][BN + 1];
    __shared__ int ra[BM], rb[BM];

    int row0 = blockIdx.x * BM;
    int col0 = blockIdx.y * BN;
    int tid  = threadIdx.x;

    if (tid < BM) {
        int gr = row0 + tid;
        ra[tid] = (gr < rows) ? b2a[gr] : 0;
    } else if (tid < 2 * BM) {
        int m = tid - BM;
        int gr = row0 + m;
        rb[m] = (gr < rows) ? b2revb[gr] : 0;
    }
    __syncthreads();

    int tm0 = (tid >> 4) * 4;
    int tn0 = (tid & 15) * 4;
    float acc[4][4] = {};

    for (int k0 = 0; k0 < BFD; k0 += BK) {
#pragma unroll
        for (int l = 0; l < 4; ++l) {
            int idx = tid + l * 256;
            int m   = idx >> 4;
            int k   = idx & 15;
            int gk  = k0 + k;
            float v = 0.0f;
            int gr = row0 + m;
            if (gr < rows && gk < BFD) v = FB[(long)gr * BFD + gk];
            Xs[k][m] = v;
            float w = 0.0f;
            int gc = col0 + m;
            if (gc < 150 && gk < BFD) w = WiB[(long)(c0 + gc) * BFD + gk];
            Ws[k][m] = w;
        }
        __syncthreads();
#pragma unroll
        for (int kk = 0; kk < BK; ++kk) {
            float xr[4], wr[4];
#pragma unroll
            for (int i = 0; i < 4; ++i) xr[i] = Xs[kk][tm0 + i];
#pragma unroll
            for (int j = 0; j < 4; ++j) wr[j] = Ws[kk][tn0 + j];
#pragma unroll
            for (int i = 0; i < 4; ++i)
#pragma unroll
                for (int j = 0; j < 4; ++j)
                    acc[i][j] += xr[i] * wr[j];
        }
        __syncthreads();
    }

#pragma unroll
    for (int i = 0; i < 4; ++i) {
        int gr = row0 + tm0 + i;
        if (gr >= rows) continue;
        int a  = ra[tm0 + i];
        int rv = rb[tm0 + i];
#pragma unroll
        for (int j = 0; j < 4; ++j) {
            int cn = col0 + tn0 + j;
            if (cn >= 150) continue;
            float ib = fmaxf(acc[i][j], 0.0f);
            float v  = ib + Th[(long)a * 150 + cn] - Vsrc[(long)rv * vstride + cn];
            P[(long)gr * 300 + c0 + cn] = fmaxf(v, 0.0f);
        }
    }
}

// dst[a,h] (+)= sum_i(mb[a2b[a,i],h]) * max_i(...)
template<bool ADD>
__global__ void aggregate(const float* __restrict__ mb, const int* __restrict__ a2b,
                          float* __restrict__ dst)
{
    long idx = (long)blockIdx.x * blockDim.x + threadIdx.x;
    if (idx >= (long)AA * HH) return;
    int a = (int)(idx / HH);
    int h = (int)(idx - (long)a * HH);
    const int* nb = a2b + (long)a * NBB;
    float s = 0.0f, mx = -INFINITY;
#pragma unroll
    for (int i = 0; i < NBB; ++i) {
        float v = mb[(long)nb[i] * HH + h];
        s += v;
        mx = fmaxf(mx, v);
    }
    float r = s * mx;
    if (ADD) r += dst[idx];
    dst[idx] = r;
}

__global__ void msgx_kernel(const float* __restrict__ node, const float* __restrict__ gbias,
                            float* __restrict__ msgx)
{
    long idx = (long)blockIdx.x * blockDim.x + threadIdx.x;
    if (idx >= (long)MLR * HH) return;
    int h = (int)(idx % HH);
    msgx[idx] = fmaxf(node[idx + HH] + gbias[h], 0.0f);
}

__global__ void h0_kernel(const float* __restrict__ node, float* __restrict__ hf,
                          float* __restrict__ hb)
{
    int idx = blockIdx.x * blockDim.x + threadIdx.x;
    if (idx >= MMOL * HH) return;
    int m = idx / HH;
    int h = idx - m * HH;
    long base = (long)(1 + m * LATM) * HH + h;
    float mx = -INFINITY;
    for (int t = 0; t < LATM; ++t) mx = fmaxf(mx, node[base + (long)t * HH]);
    hf[idx] = mx;
    hb[idx] = mx;
}

// One GRU step, one direction. 8 molecules/block, 960 threads, grid 32.
// gout is this direction's private [ML, 300] buffer.
__global__ __launch_bounds__(960)
void gru_step(const float* __restrict__ Whh, const float* __restrict__ bhh,
              const float* __restrict__ gi, float* __restrict__ h,
              float* __restrict__ gout, int t)
{
    const int m0 = blockIdx.x * 8;
    __shared__ float hs[8][HH];
    __shared__ float ghs[8][3 * HH];

    int tid = threadIdx.x;
    for (int i = tid; i < 8 * HH; i += 960) {
        int mm = i / HH, hh = i - mm * HH;
        hs[mm][hh] = h[(long)(m0 + mm) * HH + hh];
    }
    __syncthreads();

    if (tid < 3 * HH) {
        float acc[8] = {};
        const float* wrow = Whh + (long)tid * HH;
#pragma unroll 4
        for (int k = 0; k < HH; ++k) {
            float w = wrow[k];
#pragma unroll
            for (int mm = 0; mm < 8; ++mm) acc[mm] += w * hs[mm][k];
        }
        float bb = bhh[tid];
#pragma unroll
        for (int mm = 0; mm < 8; ++mm) ghs[mm][tid] = acc[mm] + bb;
    }
    __syncthreads();

    if (tid < HH) {
#pragma unroll
        for (int mm = 0; mm < 8; ++mm) {
            int m = m0 + mm;
            long row = (long)m * LATM + t;
            const float* g = gi + row * H3;
            float r = sigm(g[tid]           + ghs[mm][tid]);
            float z = sigm(g[HH + tid]      + ghs[mm][HH + tid]);
            float n = tanhf(g[2 * HH + tid] + r * ghs[mm][2 * HH + tid]);
            float hn = (1.0f - z) * n + z * hs[mm][tid];
            h[(long)m * HH + tid] = hn;
            gout[row * HH + tid] = hn;
        }
    }
}

__global__ void mean_kernel(const float* __restrict__ ah, float* __restrict__ out)
{
    int idx = blockIdx.x * blockDim.x + threadIdx.x;
    if (idx >= MMOL * HH) return;
    int m = idx / HH;
    int j = idx - m * HH;
    long base = (long)m * LATM * HH + j;
    float s = 0.0f;
    for (int t = 0; t < LATM; ++t) s += ah[base + (long)t * HH];
    out[idx] = s * (1.0f / LATM);
}

// ---------------------------------------------------------------------------
static inline int cdiv(long a, long b) { return (int)((a + b - 1) / b); }

extern "C" void kernel_launch(void* const* d_in, const int* in_sizes, int n_in,
                              void* d_out, int out_size, void* d_ws, size_t ws_size,
                              hipStream_t stream)
{
    const float* f_atoms  = (const float*)d_in[0];
    const float* f_bonds  = (const float*)d_in[1];
    const int*   a2b      = (const int*)d_in[2];
    const int*   b2a      = (const int*)d_in[3];
    const int*   b2revb   = (const int*)d_in[4];
    const float* W_i_atom = (const float*)d_in[5];
    const float* W_i_bond = (const float*)d_in[6];
    const float* W_h0     = (const float*)d_in[7];
    const float* W_h1     = (const float*)d_in[8];
    const float* W_lr     = (const float*)d_in[9];
    const float* gru_bias = (const float*)d_in[10];
    const float* Wih_f    = (const float*)d_in[11];
    const float* Whh_f    = (const float*)d_in[12];
    const float* bih_f    = (const float*)d_in[13];
    const float* bhh_f    = (const float*)d_in[14];
    const float* Wih_b    = (const float*)d_in[15];
    const float* Whh_b    = (const float*)d_in[16];
    const float* bih_b    = (const float*)d_in[17];
    const float* bhh_b    = (const float*)d_in[18];
    const float* W_o      = (const float*)d_in[19];
    const float* b_o      = (const float*)d_in[20];
    float* out = (float*)d_out;

    // Arena (bytes): all-fp32, exactly fits the proven ws floor (295,530,256 B).
    //   P  [B,300]  157,287,600
    //   S  [B,150]   78,643,800
    //   MA [A,300]   39,322,800
    //   TH [A,150]   19,661,400
    //   HF/HB           614,400     total = 295,530,000
    const size_t NEED = 295530000;
    if (ws_size < NEED) return;  // leaves output zeroed (diagnostic)

    char* b = (char*)d_ws;
    float* P  = (float*)b;
    float* S  = (float*)(b + 157287600);
    float* MA = (float*)(b + 235931400);
    float* TH = (float*)(b + 275254200);
    float* HF = (float*)(b + 294915600);
    float* HB = (float*)(b + 295222800);

    // Phase overlays (all verified disjoint per launch):
    float* Pia  = P + (size_t)AA * HH;      // ia_rc   [A,300] at P floats [9,830,700 ..)
    float* Pgi  = P + (size_t)AA * HH;      // gi      [ML,900] same offset, ends at P end
    float* Pgb  = P;                        // gout_b  [ML,300]
    float* Sgf  = S + (size_t)MLR * HH;     // gout_f  [ML,300] at S floats [9,830,400 ..)

    dim3 blk(256);
    const int gA = cdiv((long)AA * HH, 256);
    dim3 gmA (cdiv(AA, 64),   cdiv(HH, 64));   // [A,300]
    dim3 gmB3(cdiv(BBND, 64), cdiv(HH, 64));   // [B,300]
    dim3 gmB1(cdiv(BBND, 64), cdiv(150, 64));  // [B,150]
    dim3 gmT (cdiv(AA, 64),   cdiv(150, 64));  // [A,150]
    dim3 gmG (cdiv(MLR, 64),  cdiv(H3, 64));   // [ML,900]
    dim3 gmO (cdiv(MLR, 64),  cdiv(HH, 64));   // [ML,300]

    // 1. ma = input_atom = relu(f_atoms @ W_i_atom^T)
    gemm_nt<true, false, false><<<gmA, blk, 0, stream>>>(
        f_atoms, W_i_atom, AFD, nullptr, MA, AA, HH, AFD);
    // 2. mb0 = input_bond = relu(f_bonds @ W_i_bond^T)  -> P (contiguous)
    gemm_nt<true, false, false><<<gmB3, blk, 0, stream>>>(
        f_bonds, W_i_bond, BFD, nullptr, P, BBND, HH, BFD);

    // Depth loop: entry invariant: mb_d contiguous in P; S, TH free.
    const float* Wh[2] = { W_h0, W_h1 };
    for (int d = 0; d < 2; ++d) {
        const float* W = Wh[d];
        // a. ma += sum*max aggregate of mb_d
        aggregate<true><<<gA, blk, 0, stream>>>(P, a2b, MA);
        // b. Vw_lo = (mb_d @ W^T)[:, 0:150)  -> S
        gemm_nt<false, false, false><<<gmB1, blk, 0, stream>>>(
            P, W, HH, nullptr, S, BBND, 150, HH);
        // c. Vw_hi = (mb_d @ W^T)[:, 150:300) -> P[:, 0:150) in place (row-owned)
        vw_hi_inplace<<<cdiv(BBND, 16), blk, 0, stream>>>(P, W, BBND);
        // d. T_hi = (ma @ W^T)[:, 150:300) -> TH
        gemm_nt<false, false, false><<<gmT, blk, 0, stream>>>(
            MA, W + 150 * HH, HH, nullptr, TH, AA, 150, HH);
        // e. mb'[:, 150:300) = relu(ibRC + T_hi[b2a] - Vw_hi[b2revb]) -> P cols[150,300)
        bond_half<<<gmB1, blk, 0, stream>>>(
            f_bonds, W_i_bond, TH, P, 300, b2a, b2revb, P, 150, BBND);
        // f. T_lo
        gemm_nt<false, false, false><<<gmT, blk, 0, stream>>>(
            MA, W, HH, nullptr, TH, AA, 150, HH);
        // g. mb'[:, 0:150) -> P cols[0,150)   (reads S only; Vw_hi dead)
        bond_half<<<gmB1, blk, 0, stream>>>(
            f_bonds, W_i_bond, TH, S, 150, b2a, b2revb, P, 0, BBND);
        // -> mb_{d+1} contiguous in P
    }

    // Final aggregation: agg_f -> S [A,300]  (mb_2 dead afterwards)
    aggregate<false><<<gA, blk, 0, stream>>>(P, a2b, S);

    // ia recomputed -> Pia;  node = [agg|ma|ia] @ W_lr^T -> P[0..A*300)
    gemm_nt<true, false, false><<<gmA, blk, 0, stream>>>(
        f_atoms, W_i_atom, AFD, nullptr, Pia, AA, HH, AFD);
    gemm_nt<false, false, false><<<gmA, blk, 0, stream>>>(
        S,   W_lr,          H3, nullptr, P, AA, HH, HH);
    gemm_nt<false, false, true><<<gmA, blk, 0, stream>>>(
        MA,  W_lr + HH,     H3, nullptr, P, AA, HH, HH);
    gemm_nt<false, false, true><<<gmA, blk, 0, stream>>>(
        Pia, W_lr + 2 * HH, H3, nullptr, P, AA, HH, HH);

    // GRU prep: msg_x -> S[0..), h0 -> HF/HB   (node = P[0..))
    msgx_kernel<<<cdiv((long)MLR * HH, 256), blk, 0, stream>>>(P, gru_bias, S);
    h0_kernel<<<cdiv(MMOL * HH, 256), blk, 0, stream>>>(P, HF, HB);

    // Forward: gi_f -> Pgi (over dead ia_rc; node untouched), scan -> Sgf
    gemm_nt<false, true, false><<<gmG, blk, 0, stream>>>(
        S, Wih_f, HH, bih_f, Pgi, MLR, H3, HH);
    for (int t = 0; t < LATM; ++t)
        gru_step<<<dim3(MMOL / 8), dim3(960), 0, stream>>>(
            Whh_f, bhh_f, Pgi, HF, Sgf, t);

    // Backward: gi_b -> Pgi (msg_x still alive in S), scan -> Pgb (over dead node)
    gemm_nt<false, true, false><<<gmG, blk, 0, stream>>>(
        S, Wih_b, HH, bih_b, Pgi, MLR, H3, HH);
    for (int s = 0; s < LATM; ++s)
        gru_step<<<dim3(MMOL / 8), dim3(960), 0, stream>>>(
            Whh_b, bhh_b, Pgi, HB, Pgb, LATM - 1 - s);

    // atom_hiddens = relu(gout_f@Wo[:, :300]^T + gout_b@Wo[:, 300:]^T + b_o) -> MA
    gemm_nt<false, false, false><<<gmO, blk, 0, stream>>>(
        Sgf, W_o,      2 * HH, nullptr, MA, MLR, HH, HH);
    gemm_nt<true, true, true><<<gmO, blk, 0, stream>>>(
        Pgb, W_o + HH, 2 * HH, b_o,     MA, MLR, HH, HH);

    // mol_vecs = mean over L -> out
    mean_kernel<<<cdiv(MMOL * HH, 256), blk, 0, stream>>>(MA, out);
}

// Round 5
// 13682.571 us; speedup vs baseline: 2.0561x; 2.0561x over previous
//
#include <hip/hip_runtime.h>
#include <math.h>

// Problem constants
#define HH   300
#define H3   900
#define MMOL 256
#define LATM 128
#define AA   32769        // 1 + 256*128
#define NBB  6
#define BBND 131073       // 1 + 4*256*128
#define AFD  133
#define BFD  147
#define MLR  (MMOL * LATM)   // 32768

static __device__ __forceinline__ float sigm(float x) { return 1.0f / (1.0f + expf(-x)); }

// ---------------------------------------------------------------------------
// Tiled fp32 GEMM, 128x64 tile, BK=16, 8x4 microtile, 256 threads.
// C[rows,N] = act( X[rows,K] @ Wrow(n)=W[n*ldw .. n*ldw+K)  (+Bias) (+=C) )
// float4 fast staging when K (resp. ldw) is a multiple of 4.
// ---------------------------------------------------------------------------
template<bool RELU, bool BIAS, bool ACCUM>
__global__ __launch_bounds__(256)
void gemm_big(const float* __restrict__ X, const float* __restrict__ W, int ldw,
              const float* __restrict__ Bias, float* __restrict__ C,
              int rows, int N, int K)
{
    __shared__ float Xs[16][132];
    __shared__ float Ws[16][68];
    const int row0 = blockIdx.x * 128;
    const int col0 = blockIdx.y * 64;
    const int tid  = threadIdx.x;
    const int tm   = (tid >> 4) * 8;
    const int tn   = (tid & 15) * 4;
    const bool xv  = ((K & 3) == 0);
    const bool wv  = ((ldw & 3) == 0);

    float acc[8][4];
#pragma unroll
    for (int i = 0; i < 8; ++i)
#pragma unroll
        for (int j = 0; j < 4; ++j) acc[i][j] = 0.0f;

    for (int k0 = 0; k0 < K; k0 += 16) {
        const int rem = K - k0;
#pragma unroll
        for (int l = 0; l < 2; ++l) {
            int s = tid + l * 256;
            int r = s >> 2, kq = (s & 3) * 4;
            int gr = row0 + r;
            float v0 = 0, v1 = 0, v2 = 0, v3 = 0;
            if (gr < rows) {
                const float* xp = X + (long)gr * K + k0 + kq;
                if (xv && rem >= 16) {
                    float4 t4 = *(const float4*)xp;
                    v0 = t4.x; v1 = t4.y; v2 = t4.z; v3 = t4.w;
                } else {
                    if (kq + 0 < rem) v0 = xp[0];
                    if (kq + 1 < rem) v1 = xp[1];
                    if (kq + 2 < rem) v2 = xp[2];
                    if (kq + 3 < rem) v3 = xp[3];
                }
            }
            Xs[kq + 0][r] = v0; Xs[kq + 1][r] = v1;
            Xs[kq + 2][r] = v2; Xs[kq + 3][r] = v3;
        }
        {
            int r = tid >> 2, kq = (tid & 3) * 4;
            int gc = col0 + r;
            float v0 = 0, v1 = 0, v2 = 0, v3 = 0;
            if (gc < N) {
                const float* wp = W + (long)gc * ldw + k0 + kq;
                if (wv && rem >= 16) {
                    float4 t4 = *(const float4*)wp;
                    v0 = t4.x; v1 = t4.y; v2 = t4.z; v3 = t4.w;
                } else {
                    if (kq + 0 < rem) v0 = wp[0];
                    if (kq + 1 < rem) v1 = wp[1];
                    if (kq + 2 < rem) v2 = wp[2];
                    if (kq + 3 < rem) v3 = wp[3];
                }
            }
            Ws[kq + 0][r] = v0; Ws[kq + 1][r] = v1;
            Ws[kq + 2][r] = v2; Ws[kq + 3][r] = v3;
        }
        __syncthreads();
#pragma unroll
        for (int kk = 0; kk < 16; ++kk) {
            float4 xa = *(const float4*)&Xs[kk][tm];
            float4 xb = *(const float4*)&Xs[kk][tm + 4];
            float4 wq = *(const float4*)&Ws[kk][tn];
            float xr[8] = {xa.x, xa.y, xa.z, xa.w, xb.x, xb.y, xb.z, xb.w};
            float wr[4] = {wq.x, wq.y, wq.z, wq.w};
#pragma unroll
            for (int i = 0; i < 8; ++i)
#pragma unroll
                for (int j = 0; j < 4; ++j)
                    acc[i][j] += xr[i] * wr[j];
        }
        __syncthreads();
    }

#pragma unroll
    for (int i = 0; i < 8; ++i) {
        int gr = row0 + tm + i;
        if (gr >= rows) continue;
#pragma unroll
        for (int j = 0; j < 4; ++j) {
            int gc = col0 + tn + j;
            if (gc >= N) continue;
            float v = acc[i][j];
            if (BIAS)  v += Bias[gc];
            if (ACCUM) v += C[(long)gr * N + gc];
            if (RELU)  v = fmaxf(v, 0.0f);
            C[(long)gr * N + gc] = v;
        }
    }
}

// ---------------------------------------------------------------------------
// transpose: in[N][K] -> out[K][N]   (out[k*N+n] = in[n*K+k])
// ---------------------------------------------------------------------------
__global__ void transpose_kernel(const float* __restrict__ in, float* __restrict__ out,
                                 int N, int K)
{
    long idx = (long)blockIdx.x * blockDim.x + threadIdx.x;
    if (idx >= (long)N * K) return;
    int k = (int)(idx / N), n = (int)(idx - (long)k * N);
    out[idx] = in[(long)n * K + k];
}

// ---------------------------------------------------------------------------
// In-place: P[r, 0:150) = (P[r, 0:300) @ W^T)[:, 150:300)  via transposed WT.
// Block owns 16 rows (staged to LDS before any write -> in-place safe).
// WT[k*300 + n] = W[n*300 + k]; reads WT cols 150.. coalesced.
// ---------------------------------------------------------------------------
__global__ __launch_bounds__(256)
void vw_hi_inplace(float* __restrict__ P, const float* __restrict__ WT, int rows)
{
    __shared__ float Xs[16][304];
    const int r0  = blockIdx.x * 16;
    const int tid = threadIdx.x;
    for (int i = tid; i < 16 * 300; i += 256) {
        int r = i / 300, c = i - r * 300;
        int gr = r0 + r;
        Xs[r][c] = (gr < rows) ? P[(long)gr * 300 + c] : 0.0f;
    }
    __syncthreads();

    const int r  = tid >> 4;
    const int cg = tid & 15;
    float acc[10];
#pragma unroll
    for (int u = 0; u < 10; ++u) acc[u] = 0.0f;

    for (int k = 0; k < 300; ++k) {
        float xv = Xs[r][k];
        const float* wt = WT + (long)k * 300 + 150 + cg;
#pragma unroll
        for (int u = 0; u < 10; ++u) {
            int j = cg + 16 * u;
            if (j < 150) acc[u] += xv * wt[16 * u];
        }
    }
    int gr = r0 + r;
    if (gr < rows) {
#pragma unroll
        for (int u = 0; u < 10; ++u) {
            int j = cg + 16 * u;
            if (j < 150) P[(long)gr * 300 + j] = acc[u];
        }
    }
}

// ---------------------------------------------------------------------------
// Half-column bond update, 128x64 tiles:
//  P[b, c0+cn] = relu( relu(FB[b]@WiB[c0+cn]^T) + Th[b2a[b],cn] - Vsrc[b2revb[b]*vstride+cn] )
// cn in [0,150), K = 147 (input_bond recomputed, never stored).
// ---------------------------------------------------------------------------
__global__ __launch_bounds__(256)
void bond_half(const float* __restrict__ FB, const float* __restrict__ WiB,
               const float* __restrict__ Th, const float* __restrict__ Vsrc, int vstride,
               const int* __restrict__ b2a, const int* __restrict__ b2revb,
               float* __restrict__ P, int c0, int rows)
{
    __shared__ float Xs[16][132];
    __shared__ float Ws[16][68];
    __shared__ int ra[128], rb[128];
    const int row0 = blockIdx.x * 128;
    const int col0 = blockIdx.y * 64;
    const int tid  = threadIdx.x;

    if (tid < 128) {
        int gr = row0 + tid;
        ra[tid] = (gr < rows) ? b2a[gr] : 0;
    } else {
        int m = tid - 128;
        int gr = row0 + m;
        rb[m] = (gr < rows) ? b2revb[gr] : 0;
    }

    const int tm = (tid >> 4) * 8;
    const int tn = (tid & 15) * 4;
    float acc[8][4];
#pragma unroll
    for (int i = 0; i < 8; ++i)
#pragma unroll
        for (int j = 0; j < 4; ++j) acc[i][j] = 0.0f;

    for (int k0 = 0; k0 < BFD; k0 += 16) {
        const int rem = BFD - k0;
#pragma unroll
        for (int l = 0; l < 2; ++l) {
            int s = tid + l * 256;
            int r = s >> 2, kq = (s & 3) * 4;
            int gr = row0 + r;
            float v0 = 0, v1 = 0, v2 = 0, v3 = 0;
            if (gr < rows) {
                const float* xp = FB + (long)gr * BFD + k0 + kq;
                if (kq + 0 < rem) v0 = xp[0];
                if (kq + 1 < rem) v1 = xp[1];
                if (kq + 2 < rem) v2 = xp[2];
                if (kq + 3 < rem) v3 = xp[3];
            }
            Xs[kq + 0][r] = v0; Xs[kq + 1][r] = v1;
            Xs[kq + 2][r] = v2; Xs[kq + 3][r] = v3;
        }
        {
            int r = tid >> 2, kq = (tid & 3) * 4;
            int gc = col0 + r;
            float v0 = 0, v1 = 0, v2 = 0, v3 = 0;
            if (gc < 150) {
                const float* wp = WiB + (long)(c0 + gc) * BFD + k0 + kq;
                if (kq + 0 < rem) v0 = wp[0];
                if (kq + 1 < rem) v1 = wp[1];
                if (kq + 2 < rem) v2 = wp[2];
                if (kq + 3 < rem) v3 = wp[3];
            }
            Ws[kq + 0][r] = v0; Ws[kq + 1][r] = v1;
            Ws[kq + 2][r] = v2; Ws[kq + 3][r] = v3;
        }
        __syncthreads();
#pragma unroll
        for (int kk = 0; kk < 16; ++kk) {
            float4 xa = *(const float4*)&Xs[kk][tm];
            float4 xb = *(const float4*)&Xs[kk][tm + 4];
            float4 wq = *(const float4*)&Ws[kk][tn];
            float xr[8] = {xa.x, xa.y, xa.z, xa.w, xb.x, xb.y, xb.z, xb.w};
            float wr[4] = {wq.x, wq.y, wq.z, wq.w};
#pragma unroll
            for (int i = 0; i < 8; ++i)
#pragma unroll
                for (int j = 0; j < 4; ++j)
                    acc[i][j] += xr[i] * wr[j];
        }
        __syncthreads();
    }

#pragma unroll
    for (int i = 0; i < 8; ++i) {
        int gr = row0 + tm + i;
        if (gr >= rows) continue;
        int a  = ra[tm + i];
        int rv = rb[tm + i];
#pragma unroll
        for (int j = 0; j < 4; ++j) {
            int cn = col0 + tn + j;
            if (cn >= 150) continue;
            float ib = fmaxf(acc[i][j], 0.0f);
            float v  = ib + Th[(long)a * 150 + cn] - Vsrc[(long)rv * vstride + cn];
            P[(long)gr * 300 + c0 + cn] = fmaxf(v, 0.0f);
        }
    }
}

// dst[a,h] (+)= sum_i(mb[a2b[a,i],h]) * max_i(...)
template<bool ADD>
__global__ void aggregate(const float* __restrict__ mb, const int* __restrict__ a2b,
                          float* __restrict__ dst)
{
    long idx = (long)blockIdx.x * blockDim.x + threadIdx.x;
    if (idx >= (long)AA * HH) return;
    int a = (int)(idx / HH);
    int h = (int)(idx - (long)a * HH);
    const int* nb = a2b + (long)a * NBB;
    float s = 0.0f, mx = -INFINITY;
#pragma unroll
    for (int i = 0; i < NBB; ++i) {
        float v = mb[(long)nb[i] * HH + h];
        s += v;
        mx = fmaxf(mx, v);
    }
    float r = s * mx;
    if (ADD) r += dst[idx];
    dst[idx] = r;
}

__global__ void msgx_kernel(const float* __restrict__ node, const float* __restrict__ gbias,
                            float* __restrict__ msgx)
{
    long idx = (long)blockIdx.x * blockDim.x + threadIdx.x;
    if (idx >= (long)MLR * HH) return;
    int h = (int)(idx % HH);
    msgx[idx] = fmaxf(node[idx + HH] + gbias[h], 0.0f);
}

__global__ void h0_kernel(const float* __restrict__ node, float* __restrict__ hf)
{
    int idx = blockIdx.x * blockDim.x + threadIdx.x;
    if (idx >= MMOL * HH) return;
    int m = idx / HH;
    int h = idx - m * HH;
    long base = (long)(1 + m * LATM) * HH + h;
    float mx = -INFINITY;
    for (int t = 0; t < LATM; ++t) mx = fmaxf(mx, node[base + (long)t * HH]);
    hf[idx] = mx;
}

// ---------------------------------------------------------------------------
// Fused bidirectional GRU scan. grid (64, 2): 4 molecules/block, dir=blockIdx.y.
// All 128 timesteps inside; h resident in LDS; gi computed on the fly from
// msg_x via transposed WihT (no gi buffers, no gi GEMMs).
// ---------------------------------------------------------------------------
__global__ __launch_bounds__(1024)
void gru_scan(const float* __restrict__ WhhT_f, const float* __restrict__ WihT_f,
              const float* __restrict__ bhh_f, const float* __restrict__ bih_f,
              const float* __restrict__ WhhT_b, const float* __restrict__ WihT_b,
              const float* __restrict__ bhh_b, const float* __restrict__ bih_b,
              const float* __restrict__ msgx, const float* __restrict__ h0,
              float* __restrict__ gout_f, float* __restrict__ gout_b)
{
    const int dir = blockIdx.y;
    const float* WhhT = dir ? WhhT_b : WhhT_f;
    const float* WihT = dir ? WihT_b : WihT_f;
    const float* bhh  = dir ? bhh_b  : bhh_f;
    const float* bih  = dir ? bih_b  : bih_f;
    float* gout       = dir ? gout_b : gout_f;
    const int m0 = blockIdx.x * 4;
    const int tid = threadIdx.x;

    __shared__ float hs[4][HH];
    __shared__ float xs[4][HH];
    __shared__ float ghs[4][H3];
    __shared__ float gis[4][H3];

    for (int i = tid; i < 4 * HH; i += 1024) {
        int mm = i / HH, hh = i - mm * HH;
        hs[mm][hh] = h0[(long)(m0 + mm) * HH + hh];
    }
    __syncthreads();

    for (int s = 0; s < LATM; ++s) {
        const int t = dir ? (LATM - 1 - s) : s;
        // stage msg_x rows for this timestep
        for (int i = tid; i < 4 * HH; i += 1024) {
            int mm = i / HH, hh = i - mm * HH;
            xs[mm][hh] = msgx[((long)(m0 + mm) * LATM + t) * HH + hh];
        }
        __syncthreads();
        // phase 1: gh = hs @ WhhT + bhh ; gi = xs @ WihT + bih  (per gate-unit n)
        if (tid < H3) {
            float agh[4] = {0, 0, 0, 0};
            float agi[4] = {0, 0, 0, 0};
            const float* wh = WhhT + tid;
            const float* wi = WihT + tid;
#pragma unroll 4
            for (int k = 0; k < HH; ++k) {
                float w1 = wh[(long)k * H3];
                float w2 = wi[(long)k * H3];
#pragma unroll
                for (int mm = 0; mm < 4; ++mm) {
                    agh[mm] += hs[mm][k] * w1;
                    agi[mm] += xs[mm][k] * w2;
                }
            }
            float b1 = bhh[tid], b2 = bih[tid];
#pragma unroll
            for (int mm = 0; mm < 4; ++mm) {
                ghs[mm][tid] = agh[mm] + b1;
                gis[mm][tid] = agi[mm] + b2;
            }
        }
        __syncthreads();
        // phase 2: gates + state update + output
        for (int i = tid; i < 4 * HH; i += 1024) {
            int mm = i / HH, hh = i - mm * HH;
            float r = sigm(gis[mm][hh]          + ghs[mm][hh]);
            float z = sigm(gis[mm][HH + hh]     + ghs[mm][HH + hh]);
            float n = tanhf(gis[mm][2 * HH + hh] + r * ghs[mm][2 * HH + hh]);
            float hn = (1.0f - z) * n + z * hs[mm][hh];
            hs[mm][hh] = hn;
            gout[((long)(m0 + mm) * LATM + t) * HH + hh] = hn;
        }
        __syncthreads();
    }
}

__global__ void mean_kernel(const float* __restrict__ ah, float* __restrict__ out)
{
    int idx = blockIdx.x * blockDim.x + threadIdx.x;
    if (idx >= MMOL * HH) return;
    int m = idx / HH;
    int j = idx - m * HH;
    long base = (long)m * LATM * HH + j;
    float s = 0.0f;
    for (int t = 0; t < LATM; ++t) s += ah[base + (long)t * HH];
    out[idx] = s * (1.0f / LATM);
}

// ---------------------------------------------------------------------------
static inline int cdiv(long a, long b) { return (int)((a + b - 1) / b); }

extern "C" void kernel_launch(void* const* d_in, const int* in_sizes, int n_in,
                              void* d_out, int out_size, void* d_ws, size_t ws_size,
                              hipStream_t stream)
{
    const float* f_atoms  = (const float*)d_in[0];
    const float* f_bonds  = (const float*)d_in[1];
    const int*   a2b      = (const int*)d_in[2];
    const int*   b2a      = (const int*)d_in[3];
    const int*   b2revb   = (const int*)d_in[4];
    const float* W_i_atom = (const float*)d_in[5];
    const float* W_i_bond = (const float*)d_in[6];
    const float* W_h0     = (const float*)d_in[7];
    const float* W_h1     = (const float*)d_in[8];
    const float* W_lr     = (const float*)d_in[9];
    const float* gru_bias = (const float*)d_in[10];
    const float* Wih_f    = (const float*)d_in[11];
    const float* Whh_f    = (const float*)d_in[12];
    const float* bih_f    = (const float*)d_in[13];
    const float* bhh_f    = (const float*)d_in[14];
    const float* Wih_b    = (const float*)d_in[15];
    const float* Whh_b    = (const float*)d_in[16];
    const float* bih_b    = (const float*)d_in[17];
    const float* bhh_b    = (const float*)d_in[18];
    const float* W_o      = (const float*)d_in[19];
    const float* b_o      = (const float*)d_in[20];
    float* out = (float*)d_out;

    // fp32 arena, 16B-aligned regions, total 295,530,016 <= proven ws floor.
    //   P  @ 0            157,287,600  [B,300]
    //   S  @ 157,287,600   78,643,808  [B,150] -> later msg_x | gout_f
    //   MA @ 235,931,408   39,322,800  [A,300]
    //   TH @ 275,254,208   19,661,408  [A,150] halves -> later WhhT/WihT x2
    //   HFB@ 294,915,616      614,400  WT scratch (depth) -> later h0
    const size_t NEED = 295530016;
    if (ws_size < NEED) return;

    char* b = (char*)d_ws;
    float* P   = (float*)b;
    float* S   = (float*)(b + 157287600);
    float* MA  = (float*)(b + 235931408);
    float* TH  = (float*)(b + 275254208);
    float* HFB = (float*)(b + 294915616);

    float* Pia = P + (size_t)AA * HH;       // ia_rc [A,300] (disjoint from node)
    float* Pgb = P;                         // gout_b [ML,300]
    float* Sgf = S + (size_t)MLR * HH;      // gout_f [ML,300]
    float* WT  = HFB;                       // [300][300] depth-loop transpose
    float* HF  = HFB;                       // [M,300] h0 (after depth loop)
    float* WhhT_f = TH;                     // each 270,000 floats
    float* WihT_f = TH + 270000;
    float* WhhT_b = TH + 540000;
    float* WihT_b = TH + 810000;

    dim3 blk(256);
    const int gA = cdiv((long)AA * HH, 256);
    dim3 gmA (cdiv(AA, 128),   cdiv(HH, 64));    // [A,300]
    dim3 gmB3(cdiv(BBND, 128), cdiv(HH, 64));    // [B,300]
    dim3 gmB1(cdiv(BBND, 128), cdiv(150, 64));   // [B,150]
    dim3 gmT (cdiv(AA, 128),   cdiv(150, 64));   // [A,150]
    dim3 gmO (cdiv(MLR, 128),  cdiv(HH, 64));    // [ML,300]

    // 1. ma = input_atom ; 2. mb0 = input_bond -> P
    gemm_big<true, false, false><<<gmA, blk, 0, stream>>>(
        f_atoms, W_i_atom, AFD, nullptr, MA, AA, HH, AFD);
    gemm_big<true, false, false><<<gmB3, blk, 0, stream>>>(
        f_bonds, W_i_bond, BFD, nullptr, P, BBND, HH, BFD);

    // Depth loop (mb_d contiguous in P at entry; S, TH free)
    const float* Wh[2] = { W_h0, W_h1 };
    for (int d = 0; d < 2; ++d) {
        const float* W = Wh[d];
        aggregate<true><<<gA, blk, 0, stream>>>(P, a2b, MA);               // ma += agg
        transpose_kernel<<<cdiv(90000, 256), blk, 0, stream>>>(W, WT, 300, 300);
        gemm_big<false, false, false><<<gmB1, blk, 0, stream>>>(           // Vw_lo -> S
            P, W, HH, nullptr, S, BBND, 150, HH);
        vw_hi_inplace<<<cdiv(BBND, 16), blk, 0, stream>>>(P, WT, BBND);    // Vw_hi -> P lo
        gemm_big<false, false, false><<<gmT, blk, 0, stream>>>(            // T_hi -> TH
            MA, W + 150 * HH, HH, nullptr, TH, AA, 150, HH);
        bond_half<<<gmB1, blk, 0, stream>>>(                               // mb' hi -> P hi
            f_bonds, W_i_bond, TH, P, 300, b2a, b2revb, P, 150, BBND);
        gemm_big<false, false, false><<<gmT, blk, 0, stream>>>(            // T_lo -> TH
            MA, W, HH, nullptr, TH, AA, 150, HH);
        bond_half<<<gmB1, blk, 0, stream>>>(                               // mb' lo -> P lo
            f_bonds, W_i_bond, TH, S, 150, b2a, b2revb, P, 0, BBND);
    }

    // Final aggregation -> S [A,300]
    aggregate<false><<<gA, blk, 0, stream>>>(P, a2b, S);

    // ia recomputed -> Pia ; node = [agg|ma|ia] @ W_lr^T -> P[0..A*300)
    gemm_big<true, false, false><<<gmA, blk, 0, stream>>>(
        f_atoms, W_i_atom, AFD, nullptr, Pia, AA, HH, AFD);
    gemm_big<false, false, false><<<gmA, blk, 0, stream>>>(
        S,   W_lr,          H3, nullptr, P, AA, HH, HH);
    gemm_big<false, false, true><<<gmA, blk, 0, stream>>>(
        MA,  W_lr + HH,     H3, nullptr, P, AA, HH, HH);
    gemm_big<false, false, true><<<gmA, blk, 0, stream>>>(
        Pia, W_lr + 2 * HH, H3, nullptr, P, AA, HH, HH);

    // GRU prep: msg_x -> S, h0 -> HF (WT dead), weight transposes -> TH (T dead)
    msgx_kernel<<<cdiv((long)MLR * HH, 256), blk, 0, stream>>>(P, gru_bias, S);
    h0_kernel<<<cdiv(MMOL * HH, 256), blk, 0, stream>>>(P, HF);
    transpose_kernel<<<cdiv(270000, 256), blk, 0, stream>>>(Whh_f, WhhT_f, H3, HH);
    transpose_kernel<<<cdiv(270000, 256), blk, 0, stream>>>(Wih_f, WihT_f, H3, HH);
    transpose_kernel<<<cdiv(270000, 256), blk, 0, stream>>>(Whh_b, WhhT_b, H3, HH);
    transpose_kernel<<<cdiv(270000, 256), blk, 0, stream>>>(Wih_b, WihT_b, H3, HH);

    // Fused bidirectional scan (node dead; gout_b overwrites it)
    gru_scan<<<dim3(MMOL / 4, 2), dim3(1024), 0, stream>>>(
        WhhT_f, WihT_f, bhh_f, bih_f, WhhT_b, WihT_b, bhh_b, bih_b,
        S, HF, Sgf, Pgb);

    // atom_hiddens = relu(gout_f@Wo[:, :300]^T + gout_b@Wo[:, 300:]^T + b_o) -> MA
    gemm_big<false, false, false><<<gmO, blk, 0, stream>>>(
        Sgf, W_o,      2 * HH, nullptr, MA, MLR, HH, HH);
    gemm_big<true, true, true><<<gmO, blk, 0, stream>>>(
        Pgb, W_o + HH, 2 * HH, b_o,     MA, MLR, HH, HH);

    // mol_vecs = mean over L -> out
    mean_kernel<<<cdiv(MMOL * HH, 256), blk, 0, stream>>>(MA, out);
}

// Round 6
// 8840.208 us; speedup vs baseline: 3.1824x; 1.5478x over previous
//
#include <hip/hip_runtime.h>
#include <math.h>

// Problem constants
#define HH   300
#define H3   900
#define MMOL 256
#define LATM 128
#define AA   32769        // 1 + 256*128
#define NBB  6
#define BBND 131073       // 1 + 4*256*128
#define AFD  133
#define BFD  147
#define MLR  (MMOL * LATM)   // 32768

static __device__ __forceinline__ float sigm(float x) { return 1.0f / (1.0f + expf(-x)); }

// ---------------------------------------------------------------------------
// Tiled fp32 GEMM, 128x64 tile, BK=16, 8x4 microtile, 256 threads.
// ---------------------------------------------------------------------------
template<bool RELU, bool BIAS, bool ACCUM>
__global__ __launch_bounds__(256)
void gemm_big(const float* __restrict__ X, const float* __restrict__ W, int ldw,
              const float* __restrict__ Bias, float* __restrict__ C,
              int rows, int N, int K)
{
    __shared__ float Xs[16][132];
    __shared__ float Ws[16][68];
    const int row0 = blockIdx.x * 128;
    const int col0 = blockIdx.y * 64;
    const int tid  = threadIdx.x;
    const int tm   = (tid >> 4) * 8;
    const int tn   = (tid & 15) * 4;
    const bool xv  = ((K & 3) == 0);
    const bool wv  = ((ldw & 3) == 0);

    float acc[8][4];
#pragma unroll
    for (int i = 0; i < 8; ++i)
#pragma unroll
        for (int j = 0; j < 4; ++j) acc[i][j] = 0.0f;

    for (int k0 = 0; k0 < K; k0 += 16) {
        const int rem = K - k0;
#pragma unroll
        for (int l = 0; l < 2; ++l) {
            int s = tid + l * 256;
            int r = s >> 2, kq = (s & 3) * 4;
            int gr = row0 + r;
            float v0 = 0, v1 = 0, v2 = 0, v3 = 0;
            if (gr < rows) {
                const float* xp = X + (long)gr * K + k0 + kq;
                if (xv && rem >= 16) {
                    float4 t4 = *(const float4*)xp;
                    v0 = t4.x; v1 = t4.y; v2 = t4.z; v3 = t4.w;
                } else {
                    if (kq + 0 < rem) v0 = xp[0];
                    if (kq + 1 < rem) v1 = xp[1];
                    if (kq + 2 < rem) v2 = xp[2];
                    if (kq + 3 < rem) v3 = xp[3];
                }
            }
            Xs[kq + 0][r] = v0; Xs[kq + 1][r] = v1;
            Xs[kq + 2][r] = v2; Xs[kq + 3][r] = v3;
        }
        {
            int r = tid >> 2, kq = (tid & 3) * 4;
            int gc = col0 + r;
            float v0 = 0, v1 = 0, v2 = 0, v3 = 0;
            if (gc < N) {
                const float* wp = W + (long)gc * ldw + k0 + kq;
                if (wv && rem >= 16) {
                    float4 t4 = *(const float4*)wp;
                    v0 = t4.x; v1 = t4.y; v2 = t4.z; v3 = t4.w;
                } else {
                    if (kq + 0 < rem) v0 = wp[0];
                    if (kq + 1 < rem) v1 = wp[1];
                    if (kq + 2 < rem) v2 = wp[2];
                    if (kq + 3 < rem) v3 = wp[3];
                }
            }
            Ws[kq + 0][r] = v0; Ws[kq + 1][r] = v1;
            Ws[kq + 2][r] = v2; Ws[kq + 3][r] = v3;
        }
        __syncthreads();
#pragma unroll
        for (int kk = 0; kk < 16; ++kk) {
            float4 xa = *(const float4*)&Xs[kk][tm];
            float4 xb = *(const float4*)&Xs[kk][tm + 4];
            float4 wq = *(const float4*)&Ws[kk][tn];
            float xr[8] = {xa.x, xa.y, xa.z, xa.w, xb.x, xb.y, xb.z, xb.w};
            float wr[4] = {wq.x, wq.y, wq.z, wq.w};
#pragma unroll
            for (int i = 0; i < 8; ++i)
#pragma unroll
                for (int j = 0; j < 4; ++j)
                    acc[i][j] += xr[i] * wr[j];
        }
        __syncthreads();
    }

#pragma unroll
    for (int i = 0; i < 8; ++i) {
        int gr = row0 + tm + i;
        if (gr >= rows) continue;
#pragma unroll
        for (int j = 0; j < 4; ++j) {
            int gc = col0 + tn + j;
            if (gc >= N) continue;
            float v = acc[i][j];
            if (BIAS)  v += Bias[gc];
            if (ACCUM) v += C[(long)gr * N + gc];
            if (RELU)  v = fmaxf(v, 0.0f);
            C[(long)gr * N + gc] = v;
        }
    }
}

// transpose: in[N][K] -> out[K][N]
__global__ void transpose_kernel(const float* __restrict__ in, float* __restrict__ out,
                                 int N, int K)
{
    long idx = (long)blockIdx.x * blockDim.x + threadIdx.x;
    if (idx >= (long)N * K) return;
    int k = (int)(idx / N), n = (int)(idx - (long)k * N);
    out[idx] = in[(long)n * K + k];
}

// ---------------------------------------------------------------------------
// In-place: P[r, 0:150) = (P[r, 0:300) @ W^T)[:, 150:300) via transposed WT.
// ---------------------------------------------------------------------------
__global__ __launch_bounds__(256)
void vw_hi_inplace(float* __restrict__ P, const float* __restrict__ WT, int rows)
{
    __shared__ float Xs[16][304];
    const int r0  = blockIdx.x * 16;
    const int tid = threadIdx.x;
    for (int i = tid; i < 16 * 300; i += 256) {
        int r = i / 300, c = i - r * 300;
        int gr = r0 + r;
        Xs[r][c] = (gr < rows) ? P[(long)gr * 300 + c] : 0.0f;
    }
    __syncthreads();

    const int r  = tid >> 4;
    const int cg = tid & 15;
    float acc[10];
#pragma unroll
    for (int u = 0; u < 10; ++u) acc[u] = 0.0f;

    for (int k = 0; k < 300; ++k) {
        float xv = Xs[r][k];
        const float* wt = WT + (long)k * 300 + 150 + cg;
#pragma unroll
        for (int u = 0; u < 10; ++u) {
            int j = cg + 16 * u;
            if (j < 150) acc[u] += xv * wt[16 * u];
        }
    }
    int gr = r0 + r;
    if (gr < rows) {
#pragma unroll
        for (int u = 0; u < 10; ++u) {
            int j = cg + 16 * u;
            if (j < 150) P[(long)gr * 300 + j] = acc[u];
        }
    }
}

// ---------------------------------------------------------------------------
// Half-column bond update (128x64 tiles, K=147 recomputed input_bond)
// ---------------------------------------------------------------------------
__global__ __launch_bounds__(256)
void bond_half(const float* __restrict__ FB, const float* __restrict__ WiB,
               const float* __restrict__ Th, const float* __restrict__ Vsrc, int vstride,
               const int* __restrict__ b2a, const int* __restrict__ b2revb,
               float* __restrict__ P, int c0, int rows)
{
    __shared__ float Xs[16][132];
    __shared__ float Ws[16][68];
    __shared__ int ra[128], rb[128];
    const int row0 = blockIdx.x * 128;
    const int col0 = blockIdx.y * 64;
    const int tid  = threadIdx.x;

    if (tid < 128) {
        int gr = row0 + tid;
        ra[tid] = (gr < rows) ? b2a[gr] : 0;
    } else {
        int m = tid - 128;
        int gr = row0 + m;
        rb[m] = (gr < rows) ? b2revb[gr] : 0;
    }

    const int tm = (tid >> 4) * 8;
    const int tn = (tid & 15) * 4;
    float acc[8][4];
#pragma unroll
    for (int i = 0; i < 8; ++i)
#pragma unroll
        for (int j = 0; j < 4; ++j) acc[i][j] = 0.0f;

    for (int k0 = 0; k0 < BFD; k0 += 16) {
        const int rem = BFD - k0;
#pragma unroll
        for (int l = 0; l < 2; ++l) {
            int s = tid + l * 256;
            int r = s >> 2, kq = (s & 3) * 4;
            int gr = row0 + r;
            float v0 = 0, v1 = 0, v2 = 0, v3 = 0;
            if (gr < rows) {
                const float* xp = FB + (long)gr * BFD + k0 + kq;
                if (kq + 0 < rem) v0 = xp[0];
                if (kq + 1 < rem) v1 = xp[1];
                if (kq + 2 < rem) v2 = xp[2];
                if (kq + 3 < rem) v3 = xp[3];
            }
            Xs[kq + 0][r] = v0; Xs[kq + 1][r] = v1;
            Xs[kq + 2][r] = v2; Xs[kq + 3][r] = v3;
        }
        {
            int r = tid >> 2, kq = (tid & 3) * 4;
            int gc = col0 + r;
            float v0 = 0, v1 = 0, v2 = 0, v3 = 0;
            if (gc < 150) {
                const float* wp = WiB + (long)(c0 + gc) * BFD + k0 + kq;
                if (kq + 0 < rem) v0 = wp[0];
                if (kq + 1 < rem) v1 = wp[1];
                if (kq + 2 < rem) v2 = wp[2];
                if (kq + 3 < rem) v3 = wp[3];
            }
            Ws[kq + 0][r] = v0; Ws[kq + 1][r] = v1;
            Ws[kq + 2][r] = v2; Ws[kq + 3][r] = v3;
        }
        __syncthreads();
#pragma unroll
        for (int kk = 0; kk < 16; ++kk) {
            float4 xa = *(const float4*)&Xs[kk][tm];
            float4 xb = *(const float4*)&Xs[kk][tm + 4];
            float4 wq = *(const float4*)&Ws[kk][tn];
            float xr[8] = {xa.x, xa.y, xa.z, xa.w, xb.x, xb.y, xb.z, xb.w};
            float wr[4] = {wq.x, wq.y, wq.z, wq.w};
#pragma unroll
            for (int i = 0; i < 8; ++i)
#pragma unroll
                for (int j = 0; j < 4; ++j)
                    acc[i][j] += xr[i] * wr[j];
        }
        __syncthreads();
    }

#pragma unroll
    for (int i = 0; i < 8; ++i) {
        int gr = row0 + tm + i;
        if (gr >= rows) continue;
        int a  = ra[tm + i];
        int rv = rb[tm + i];
#pragma unroll
        for (int j = 0; j < 4; ++j) {
            int cn = col0 + tn + j;
            if (cn >= 150) continue;
            float ib = fmaxf(acc[i][j], 0.0f);
            float v  = ib + Th[(long)a * 150 + cn] - Vsrc[(long)rv * vstride + cn];
            P[(long)gr * 300 + c0 + cn] = fmaxf(v, 0.0f);
        }
    }
}

template<bool ADD>
__global__ void aggregate(const float* __restrict__ mb, const int* __restrict__ a2b,
                          float* __restrict__ dst)
{
    long idx = (long)blockIdx.x * blockDim.x + threadIdx.x;
    if (idx >= (long)AA * HH) return;
    int a = (int)(idx / HH);
    int h = (int)(idx - (long)a * HH);
    const int* nb = a2b + (long)a * NBB;
    float s = 0.0f, mx = -INFINITY;
#pragma unroll
    for (int i = 0; i < NBB; ++i) {
        float v = mb[(long)nb[i] * HH + h];
        s += v;
        mx = fmaxf(mx, v);
    }
    float r = s * mx;
    if (ADD) r += dst[idx];
    dst[idx] = r;
}

__global__ void msgx_kernel(const float* __restrict__ node, const float* __restrict__ gbias,
                            float* __restrict__ msgx)
{
    long idx = (long)blockIdx.x * blockDim.x + threadIdx.x;
    if (idx >= (long)MLR * HH) return;
    int h = (int)(idx % HH);
    msgx[idx] = fmaxf(node[idx + HH] + gbias[h], 0.0f);
}

__global__ void h0_kernel(const float* __restrict__ node, float* __restrict__ hf)
{
    int idx = blockIdx.x * blockDim.x + threadIdx.x;
    if (idx >= MMOL * HH) return;
    int m = idx / HH;
    int h = idx - m * HH;
    long base = (long)(1 + m * LATM) * HH + h;
    float mx = -INFINITY;
    for (int t = 0; t < LATM; ++t) mx = fmaxf(mx, node[base + (long)t * HH]);
    hf[idx] = mx;
}

// ---------------------------------------------------------------------------
// Fused bidirectional GRU scan v2. grid (64, 2): 4 mols/block, dir=blockIdx.y.
// Phase1: 900 threads, each gate-unit n accumulates gh & gi over k with
// float4 LDS broadcasts (ds_read_b128) and 8 pipelined L2 weight loads per
// 4-k chunk. r/z gates stored pre-summed; n-gate parts kept separate.
// ---------------------------------------------------------------------------
__global__ __launch_bounds__(1024)
void gru_scan(const float* __restrict__ WhhT_f, const float* __restrict__ WihT_f,
              const float* __restrict__ bhh_f, const float* __restrict__ bih_f,
              const float* __restrict__ WhhT_b, const float* __restrict__ WihT_b,
              const float* __restrict__ bhh_b, const float* __restrict__ bih_b,
              const float* __restrict__ msgx, const float* __restrict__ h0,
              float* __restrict__ gout_f, float* __restrict__ gout_b)
{
    const int dir = blockIdx.y;
    const float* WhhT = dir ? WhhT_b : WhhT_f;
    const float* WihT = dir ? WihT_b : WihT_f;
    const float* bhh  = dir ? bhh_b  : bhh_f;
    const float* bih  = dir ? bih_b  : bih_f;
    float* gout       = dir ? gout_b : gout_f;
    const int m0  = blockIdx.x * 4;
    const int tid = threadIdx.x;

    __shared__ float hs[4][304];    // rows 16B-aligned for float4 reads
    __shared__ float xs[4][304];
    __shared__ float ghs[4][H3];    // n<600: gh+gi+biases ; n>=600: gh_n + bhh
    __shared__ float gin[4][HH];    // gi_n + bih

    // biases hoisted (constant across steps)
    float bsum = 0.0f, b1 = 0.0f, b2 = 0.0f;
    if (tid < H3) {
        b1 = bhh[tid];
        b2 = bih[tid];
        bsum = b1 + b2;
    }

    // load h0 (vectorized: 300 float4 items)
    for (int i = tid; i < 300; i += 1024) {
        int mm = i / 75, q = (i - mm * 75) * 4;
        *(float4*)&hs[mm][q] = *(const float4*)&h0[(long)(m0 + mm) * HH + q];
    }
    // stage first timestep's msg_x
    {
        int t0 = dir ? (LATM - 1) : 0;
        for (int i = tid; i < 300; i += 1024) {
            int mm = i / 75, q = (i - mm * 75) * 4;
            *(float4*)&xs[mm][q] =
                *(const float4*)&msgx[((long)(m0 + mm) * LATM + t0) * HH + q];
        }
    }
    __syncthreads();

    for (int s = 0; s < LATM; ++s) {
        const int t = dir ? (LATM - 1 - s) : s;

        // ---- phase 1: gh, gi for all 900 gate units ----
        if (tid < H3) {
            const int n = tid;
            float agh0 = 0, agh1 = 0, agh2 = 0, agh3 = 0;
            float agi0 = 0, agi1 = 0, agi2 = 0, agi3 = 0;
            const float* wh = WhhT + n;
            const float* wi = WihT + n;
#pragma unroll 2
            for (int k0 = 0; k0 < HH; k0 += 4) {
                float w0 = wh[(long)(k0 + 0) * H3];
                float w1 = wh[(long)(k0 + 1) * H3];
                float w2 = wh[(long)(k0 + 2) * H3];
                float w3 = wh[(long)(k0 + 3) * H3];
                float u0 = wi[(long)(k0 + 0) * H3];
                float u1 = wi[(long)(k0 + 1) * H3];
                float u2 = wi[(long)(k0 + 2) * H3];
                float u3 = wi[(long)(k0 + 3) * H3];
                float4 h0v = *(const float4*)&hs[0][k0];
                float4 h1v = *(const float4*)&hs[1][k0];
                float4 h2v = *(const float4*)&hs[2][k0];
                float4 h3v = *(const float4*)&hs[3][k0];
                float4 x0v = *(const float4*)&xs[0][k0];
                float4 x1v = *(const float4*)&xs[1][k0];
                float4 x2v = *(const float4*)&xs[2][k0];
                float4 x3v = *(const float4*)&xs[3][k0];
                agh0 += h0v.x * w0 + h0v.y * w1 + h0v.z * w2 + h0v.w * w3;
                agh1 += h1v.x * w0 + h1v.y * w1 + h1v.z * w2 + h1v.w * w3;
                agh2 += h2v.x * w0 + h2v.y * w1 + h2v.z * w2 + h2v.w * w3;
                agh3 += h3v.x * w0 + h3v.y * w1 + h3v.z * w2 + h3v.w * w3;
                agi0 += x0v.x * u0 + x0v.y * u1 + x0v.z * u2 + x0v.w * u3;
                agi1 += x1v.x * u0 + x1v.y * u1 + x1v.z * u2 + x1v.w * u3;
                agi2 += x2v.x * u0 + x2v.y * u1 + x2v.z * u2 + x2v.w * u3;
                agi3 += x3v.x * u0 + x3v.y * u1 + x3v.z * u2 + x3v.w * u3;
            }
            if (n < 600) {           // r,z gates: sum is all we need
                ghs[0][n] = agh0 + agi0 + bsum;
                ghs[1][n] = agh1 + agi1 + bsum;
                ghs[2][n] = agh2 + agi2 + bsum;
                ghs[3][n] = agh3 + agi3 + bsum;
            } else {                 // n-gate: keep parts separate
                ghs[0][n] = agh0 + b1;  gin[0][n - 600] = agi0 + b2;
                ghs[1][n] = agh1 + b1;  gin[1][n - 600] = agi1 + b2;
                ghs[2][n] = agh2 + b1;  gin[2][n - 600] = agi2 + b2;
                ghs[3][n] = agh3 + b1;  gin[3][n - 600] = agi3 + b2;
            }
        }
        __syncthreads();

        // ---- phase 2: gates, state update, output; plus stage next msg_x ----
        for (int i = tid; i < 4 * HH; i += 1024) {
            int mm = i / HH, hh = i - mm * HH;
            float r  = sigm(ghs[mm][hh]);
            float z  = sigm(ghs[mm][HH + hh]);
            float nn = tanhf(gin[mm][hh] + r * ghs[mm][2 * HH + hh]);
            float hn = (1.0f - z) * nn + z * hs[mm][hh];
            hs[mm][hh] = hn;
            gout[((long)(m0 + mm) * LATM + t) * HH + hh] = hn;
        }
        if (s + 1 < LATM) {
            int tn_ = dir ? (LATM - 2 - s) : (s + 1);
            for (int i = tid; i < 300; i += 1024) {
                int mm = i / 75, q = (i - mm * 75) * 4;
                *(float4*)&xs[mm][q] =
                    *(const float4*)&msgx[((long)(m0 + mm) * LATM + tn_) * HH + q];
            }
        }
        __syncthreads();
    }
}

__global__ void mean_kernel(const float* __restrict__ ah, float* __restrict__ out)
{
    int idx = blockIdx.x * blockDim.x + threadIdx.x;
    if (idx >= MMOL * HH) return;
    int m = idx / HH;
    int j = idx - m * HH;
    long base = (long)m * LATM * HH + j;
    float s = 0.0f;
    for (int t = 0; t < LATM; ++t) s += ah[base + (long)t * HH];
    out[idx] = s * (1.0f / LATM);
}

// ---------------------------------------------------------------------------
static inline int cdiv(long a, long b) { return (int)((a + b - 1) / b); }

extern "C" void kernel_launch(void* const* d_in, const int* in_sizes, int n_in,
                              void* d_out, int out_size, void* d_ws, size_t ws_size,
                              hipStream_t stream)
{
    const float* f_atoms  = (const float*)d_in[0];
    const float* f_bonds  = (const float*)d_in[1];
    const int*   a2b      = (const int*)d_in[2];
    const int*   b2a      = (const int*)d_in[3];
    const int*   b2revb   = (const int*)d_in[4];
    const float* W_i_atom = (const float*)d_in[5];
    const float* W_i_bond = (const float*)d_in[6];
    const float* W_h0     = (const float*)d_in[7];
    const float* W_h1     = (const float*)d_in[8];
    const float* W_lr     = (const float*)d_in[9];
    const float* gru_bias = (const float*)d_in[10];
    const float* Wih_f    = (const float*)d_in[11];
    const float* Whh_f    = (const float*)d_in[12];
    const float* bih_f    = (const float*)d_in[13];
    const float* bhh_f    = (const float*)d_in[14];
    const float* Wih_b    = (const float*)d_in[15];
    const float* Whh_b    = (const float*)d_in[16];
    const float* bih_b    = (const float*)d_in[17];
    const float* bhh_b    = (const float*)d_in[18];
    const float* W_o      = (const float*)d_in[19];
    const float* b_o      = (const float*)d_in[20];
    float* out = (float*)d_out;

    // fp32 arena (same as round 4; total 295,530,016 <= proven ws floor)
    const size_t NEED = 295530016;
    if (ws_size < NEED) return;

    char* b = (char*)d_ws;
    float* P   = (float*)b;
    float* S   = (float*)(b + 157287600);
    float* MA  = (float*)(b + 235931408);
    float* TH  = (float*)(b + 275254208);
    float* HFB = (float*)(b + 294915616);

    float* Pia = P + (size_t)AA * HH;       // ia_rc [A,300]
    float* Pgb = P;                         // gout_b [ML,300]
    float* Sgf = S + (size_t)MLR * HH;      // gout_f [ML,300]
    float* WT  = HFB;                       // depth-loop 300x300 transpose
    float* HF  = HFB;                       // h0 [M,300] (after depth loop)
    float* WhhT_f = TH;                     // 270,000 floats each
    float* WihT_f = TH + 270000;
    float* WhhT_b = TH + 540000;
    float* WihT_b = TH + 810000;

    dim3 blk(256);
    const int gA = cdiv((long)AA * HH, 256);
    dim3 gmA (cdiv(AA, 128),   cdiv(HH, 64));
    dim3 gmB3(cdiv(BBND, 128), cdiv(HH, 64));
    dim3 gmB1(cdiv(BBND, 128), cdiv(150, 64));
    dim3 gmT (cdiv(AA, 128),   cdiv(150, 64));
    dim3 gmO (cdiv(MLR, 128),  cdiv(HH, 64));

    // 1. ma = input_atom ; 2. mb0 = input_bond -> P
    gemm_big<true, false, false><<<gmA, blk, 0, stream>>>(
        f_atoms, W_i_atom, AFD, nullptr, MA, AA, HH, AFD);
    gemm_big<true, false, false><<<gmB3, blk, 0, stream>>>(
        f_bonds, W_i_bond, BFD, nullptr, P, BBND, HH, BFD);

    // Depth loop
    const float* Wh[2] = { W_h0, W_h1 };
    for (int d = 0; d < 2; ++d) {
        const float* W = Wh[d];
        aggregate<true><<<gA, blk, 0, stream>>>(P, a2b, MA);
        transpose_kernel<<<cdiv(90000, 256), blk, 0, stream>>>(W, WT, 300, 300);
        gemm_big<false, false, false><<<gmB1, blk, 0, stream>>>(
            P, W, HH, nullptr, S, BBND, 150, HH);
        vw_hi_inplace<<<cdiv(BBND, 16), blk, 0, stream>>>(P, WT, BBND);
        gemm_big<false, false, false><<<gmT, blk, 0, stream>>>(
            MA, W + 150 * HH, HH, nullptr, TH, AA, 150, HH);
        bond_half<<<gmB1, blk, 0, stream>>>(
            f_bonds, W_i_bond, TH, P, 300, b2a, b2revb, P, 150, BBND);
        gemm_big<false, false, false><<<gmT, blk, 0, stream>>>(
            MA, W, HH, nullptr, TH, AA, 150, HH);
        bond_half<<<gmB1, blk, 0, stream>>>(
            f_bonds, W_i_bond, TH, S, 150, b2a, b2revb, P, 0, BBND);
    }

    // Final aggregation -> S
    aggregate<false><<<gA, blk, 0, stream>>>(P, a2b, S);

    // ia recomputed -> Pia ; node -> P
    gemm_big<true, false, false><<<gmA, blk, 0, stream>>>(
        f_atoms, W_i_atom, AFD, nullptr, Pia, AA, HH, AFD);
    gemm_big<false, false, false><<<gmA, blk, 0, stream>>>(
        S,   W_lr,          H3, nullptr, P, AA, HH, HH);
    gemm_big<false, false, true><<<gmA, blk, 0, stream>>>(
        MA,  W_lr + HH,     H3, nullptr, P, AA, HH, HH);
    gemm_big<false, false, true><<<gmA, blk, 0, stream>>>(
        Pia, W_lr + 2 * HH, H3, nullptr, P, AA, HH, HH);

    // GRU prep
    msgx_kernel<<<cdiv((long)MLR * HH, 256), blk, 0, stream>>>(P, gru_bias, S);
    h0_kernel<<<cdiv(MMOL * HH, 256), blk, 0, stream>>>(P, HF);
    transpose_kernel<<<cdiv(270000, 256), blk, 0, stream>>>(Whh_f, WhhT_f, H3, HH);
    transpose_kernel<<<cdiv(270000, 256), blk, 0, stream>>>(Wih_f, WihT_f, H3, HH);
    transpose_kernel<<<cdiv(270000, 256), blk, 0, stream>>>(Whh_b, WhhT_b, H3, HH);
    transpose_kernel<<<cdiv(270000, 256), blk, 0, stream>>>(Wih_b, WihT_b, H3, HH);

    // Fused bidirectional scan
    gru_scan<<<dim3(MMOL / 4, 2), dim3(1024), 0, stream>>>(
        WhhT_f, WihT_f, bhh_f, bih_f, WhhT_b, WihT_b, bhh_b, bih_b,
        S, HF, Sgf, Pgb);

    // atom_hiddens -> MA
    gemm_big<false, false, false><<<gmO, blk, 0, stream>>>(
        Sgf, W_o,      2 * HH, nullptr, MA, MLR, HH, HH);
    gemm_big<true, true, true><<<gmO, blk, 0, stream>>>(
        Pgb, W_o + HH, 2 * HH, b_o,     MA, MLR, HH, HH);

    // mol_vecs -> out
    mean_kernel<<<cdiv(MMOL * HH, 256), blk, 0, stream>>>(MA, out);
}

// Round 7
// 6328.970 us; speedup vs baseline: 4.4451x; 1.3968x over previous
//
#include <hip/hip_runtime.h>
#include <math.h>

// Problem constants
#define HH   300
#define H3   900
#define MMOL 256
#define LATM 128
#define AA   32769        // 1 + 256*128
#define NBB  6
#define BBND 131073       // 1 + 4*256*128
#define AFD  133
#define BFD  147
#define MLR  (MMOL * LATM)   // 32768

static __device__ __forceinline__ float sigm(float x) { return 1.0f / (1.0f + expf(-x)); }

// ---------------------------------------------------------------------------
// Tiled fp32 GEMM, 128x64 tile, BK=16, 8x4 microtile, 256 threads.
// C[rows,N] = act( X[rows, ldx-strided] @ Wrow(n)=W[n*ldw ..]  (+Bias) (+=C) )
// ---------------------------------------------------------------------------
template<bool RELU, bool BIAS, bool ACCUM>
__global__ __launch_bounds__(256)
void gemm_big(const float* __restrict__ X, int ldx, const float* __restrict__ W, int ldw,
              const float* __restrict__ Bias, float* __restrict__ C,
              int rows, int N, int K)
{
    __shared__ float Xs[16][132];
    __shared__ float Ws[16][68];
    const int row0 = blockIdx.x * 128;
    const int col0 = blockIdx.y * 64;
    const int tid  = threadIdx.x;
    const int tm   = (tid >> 4) * 8;
    const int tn   = (tid & 15) * 4;
    const bool xv  = ((ldx & 3) == 0);
    const bool wv  = ((ldw & 3) == 0);

    float acc[8][4];
#pragma unroll
    for (int i = 0; i < 8; ++i)
#pragma unroll
        for (int j = 0; j < 4; ++j) acc[i][j] = 0.0f;

    for (int k0 = 0; k0 < K; k0 += 16) {
        const int rem = K - k0;
#pragma unroll
        for (int l = 0; l < 2; ++l) {
            int s = tid + l * 256;
            int r = s >> 2, kq = (s & 3) * 4;
            int gr = row0 + r;
            float v0 = 0, v1 = 0, v2 = 0, v3 = 0;
            if (gr < rows) {
                const float* xp = X + (long)gr * ldx + k0 + kq;
                if (xv && rem >= 16) {
                    float4 t4 = *(const float4*)xp;
                    v0 = t4.x; v1 = t4.y; v2 = t4.z; v3 = t4.w;
                } else {
                    if (kq + 0 < rem) v0 = xp[0];
                    if (kq + 1 < rem) v1 = xp[1];
                    if (kq + 2 < rem) v2 = xp[2];
                    if (kq + 3 < rem) v3 = xp[3];
                }
            }
            Xs[kq + 0][r] = v0; Xs[kq + 1][r] = v1;
            Xs[kq + 2][r] = v2; Xs[kq + 3][r] = v3;
        }
        {
            int r = tid >> 2, kq = (tid & 3) * 4;
            int gc = col0 + r;
            float v0 = 0, v1 = 0, v2 = 0, v3 = 0;
            if (gc < N) {
                const float* wp = W + (long)gc * ldw + k0 + kq;
                if (wv && rem >= 16) {
                    float4 t4 = *(const float4*)wp;
                    v0 = t4.x; v1 = t4.y; v2 = t4.z; v3 = t4.w;
                } else {
                    if (kq + 0 < rem) v0 = wp[0];
                    if (kq + 1 < rem) v1 = wp[1];
                    if (kq + 2 < rem) v2 = wp[2];
                    if (kq + 3 < rem) v3 = wp[3];
                }
            }
            Ws[kq + 0][r] = v0; Ws[kq + 1][r] = v1;
            Ws[kq + 2][r] = v2; Ws[kq + 3][r] = v3;
        }
        __syncthreads();
#pragma unroll
        for (int kk = 0; kk < 16; ++kk) {
            float4 xa = *(const float4*)&Xs[kk][tm];
            float4 xb = *(const float4*)&Xs[kk][tm + 4];
            float4 wq = *(const float4*)&Ws[kk][tn];
            float xr[8] = {xa.x, xa.y, xa.z, xa.w, xb.x, xb.y, xb.z, xb.w};
            float wr[4] = {wq.x, wq.y, wq.z, wq.w};
#pragma unroll
            for (int i = 0; i < 8; ++i)
#pragma unroll
                for (int j = 0; j < 4; ++j)
                    acc[i][j] += xr[i] * wr[j];
        }
        __syncthreads();
    }

#pragma unroll
    for (int i = 0; i < 8; ++i) {
        int gr = row0 + tm + i;
        if (gr >= rows) continue;
#pragma unroll
        for (int j = 0; j < 4; ++j) {
            int gc = col0 + tn + j;
            if (gc >= N) continue;
            float v = acc[i][j];
            if (BIAS)  v += Bias[gc];
            if (ACCUM) v += C[(long)gr * N + gc];
            if (RELU)  v = fmaxf(v, 0.0f);
            C[(long)gr * N + gc] = v;
        }
    }
}

// transpose: in[N][K] -> out[K][N]
__global__ void transpose_kernel(const float* __restrict__ in, float* __restrict__ out,
                                 int N, int K)
{
    long idx = (long)blockIdx.x * blockDim.x + threadIdx.x;
    if (idx >= (long)N * K) return;
    int k = (int)(idx / N), n = (int)(idx - (long)k * N);
    out[idx] = in[(long)n * K + k];
}

// ---------------------------------------------------------------------------
// In-place: P[r, 0:150) = (P[r, 0:300) @ W^T)[:, 150:300) via transposed WT.
// ---------------------------------------------------------------------------
__global__ __launch_bounds__(256)
void vw_hi_inplace(float* __restrict__ P, const float* __restrict__ WT, int rows)
{
    __shared__ float Xs[16][304];
    const int r0  = blockIdx.x * 16;
    const int tid = threadIdx.x;
    for (int i = tid; i < 16 * 300; i += 256) {
        int r = i / 300, c = i - r * 300;
        int gr = r0 + r;
        Xs[r][c] = (gr < rows) ? P[(long)gr * 300 + c] : 0.0f;
    }
    __syncthreads();

    const int r  = tid >> 4;
    const int cg = tid & 15;
    float acc[10];
#pragma unroll
    for (int u = 0; u < 10; ++u) acc[u] = 0.0f;

    for (int k = 0; k < 300; ++k) {
        float xv = Xs[r][k];
        const float* wt = WT + (long)k * 300 + 150 + cg;
#pragma unroll
        for (int u = 0; u < 10; ++u) {
            int j = cg + 16 * u;
            if (j < 150) acc[u] += xv * wt[16 * u];
        }
    }
    int gr = r0 + r;
    if (gr < rows) {
#pragma unroll
        for (int u = 0; u < 10; ++u) {
            int j = cg + 16 * u;
            if (j < 150) P[(long)gr * 300 + j] = acc[u];
        }
    }
}

// ---------------------------------------------------------------------------
// Half-column bond update (128x64 tiles, K=147 recomputed input_bond)
// ---------------------------------------------------------------------------
__global__ __launch_bounds__(256)
void bond_half(const float* __restrict__ FB, const float* __restrict__ WiB,
               const float* __restrict__ Th, const float* __restrict__ Vsrc, int vstride,
               const int* __restrict__ b2a, const int* __restrict__ b2revb,
               float* __restrict__ P, int c0, int rows)
{
    __shared__ float Xs[16][132];
    __shared__ float Ws[16][68];
    __shared__ int ra[128], rb[128];
    const int row0 = blockIdx.x * 128;
    const int col0 = blockIdx.y * 64;
    const int tid  = threadIdx.x;

    if (tid < 128) {
        int gr = row0 + tid;
        ra[tid] = (gr < rows) ? b2a[gr] : 0;
    } else {
        int m = tid - 128;
        int gr = row0 + m;
        rb[m] = (gr < rows) ? b2revb[gr] : 0;
    }

    const int tm = (tid >> 4) * 8;
    const int tn = (tid & 15) * 4;
    float acc[8][4];
#pragma unroll
    for (int i = 0; i < 8; ++i)
#pragma unroll
        for (int j = 0; j < 4; ++j) acc[i][j] = 0.0f;

    for (int k0 = 0; k0 < BFD; k0 += 16) {
        const int rem = BFD - k0;
#pragma unroll
        for (int l = 0; l < 2; ++l) {
            int s = tid + l * 256;
            int r = s >> 2, kq = (s & 3) * 4;
            int gr = row0 + r;
            float v0 = 0, v1 = 0, v2 = 0, v3 = 0;
            if (gr < rows) {
                const float* xp = FB + (long)gr * BFD + k0 + kq;
                if (kq + 0 < rem) v0 = xp[0];
                if (kq + 1 < rem) v1 = xp[1];
                if (kq + 2 < rem) v2 = xp[2];
                if (kq + 3 < rem) v3 = xp[3];
            }
            Xs[kq + 0][r] = v0; Xs[kq + 1][r] = v1;
            Xs[kq + 2][r] = v2; Xs[kq + 3][r] = v3;
        }
        {
            int r = tid >> 2, kq = (tid & 3) * 4;
            int gc = col0 + r;
            float v0 = 0, v1 = 0, v2 = 0, v3 = 0;
            if (gc < 150) {
                const float* wp = WiB + (long)(c0 + gc) * BFD + k0 + kq;
                if (kq + 0 < rem) v0 = wp[0];
                if (kq + 1 < rem) v1 = wp[1];
                if (kq + 2 < rem) v2 = wp[2];
                if (kq + 3 < rem) v3 = wp[3];
            }
            Ws[kq + 0][r] = v0; Ws[kq + 1][r] = v1;
            Ws[kq + 2][r] = v2; Ws[kq + 3][r] = v3;
        }
        __syncthreads();
#pragma unroll
        for (int kk = 0; kk < 16; ++kk) {
            float4 xa = *(const float4*)&Xs[kk][tm];
            float4 xb = *(const float4*)&Xs[kk][tm + 4];
            float4 wq = *(const float4*)&Ws[kk][tn];
            float xr[8] = {xa.x, xa.y, xa.z, xa.w, xb.x, xb.y, xb.z, xb.w};
            float wr[4] = {wq.x, wq.y, wq.z, wq.w};
#pragma unroll
            for (int i = 0; i < 8; ++i)
#pragma unroll
                for (int j = 0; j < 4; ++j)
                    acc[i][j] += xr[i] * wr[j];
        }
        __syncthreads();
    }

#pragma unroll
    for (int i = 0; i < 8; ++i) {
        int gr = row0 + tm + i;
        if (gr >= rows) continue;
        int a  = ra[tm + i];
        int rv = rb[tm + i];
#pragma unroll
        for (int j = 0; j < 4; ++j) {
            int cn = col0 + tn + j;
            if (cn >= 150) continue;
            float ib = fmaxf(acc[i][j], 0.0f);
            float v  = ib + Th[(long)a * 150 + cn] - Vsrc[(long)rv * vstride + cn];
            P[(long)gr * 300 + c0 + cn] = fmaxf(v, 0.0f);
        }
    }
}

template<bool ADD>
__global__ void aggregate(const float* __restrict__ mb, const int* __restrict__ a2b,
                          float* __restrict__ dst)
{
    long idx = (long)blockIdx.x * blockDim.x + threadIdx.x;
    if (idx >= (long)AA * HH) return;
    int a = (int)(idx / HH);
    int h = (int)(idx - (long)a * HH);
    const int* nb = a2b + (long)a * NBB;
    float s = 0.0f, mx = -INFINITY;
#pragma unroll
    for (int i = 0; i < NBB; ++i) {
        float v = mb[(long)nb[i] * HH + h];
        s += v;
        mx = fmaxf(mx, v);
    }
    float r = s * mx;
    if (ADD) r += dst[idx];
    dst[idx] = r;
}

__global__ void msgx_kernel(const float* __restrict__ node, const float* __restrict__ gbias,
                            float* __restrict__ msgx)
{
    long idx = (long)blockIdx.x * blockDim.x + threadIdx.x;
    if (idx >= (long)MLR * HH) return;
    int h = (int)(idx % HH);
    msgx[idx] = fmaxf(node[idx + HH] + gbias[h], 0.0f);
}

__global__ void h0_kernel(const float* __restrict__ node, float* __restrict__ hf)
{
    int idx = blockIdx.x * blockDim.x + threadIdx.x;
    if (idx >= MMOL * HH) return;
    int m = idx / HH;
    int h = idx - m * HH;
    long base = (long)(1 + m * LATM) * HH + h;
    float mx = -INFINITY;
    for (int t = 0; t < LATM; ++t) mx = fmaxf(mx, node[base + (long)t * HH]);
    hf[idx] = mx;
}

// ---------------------------------------------------------------------------
// GRU scan v3: gi precomputed. 256 blocks, 2 mols/block, XCD-pinned dirs
// (dir 0 -> XCDs 0-3, dir 1 -> XCDs 4-7: 1.08 MB WhhT resident per XCD L2).
// Per step: gh = h @ WhhT (900 threads, coalesced column loads), then gates.
// gout written in-place into gi[t][0:300] after last read of that slot.
// ---------------------------------------------------------------------------
__global__ __launch_bounds__(1024)
void gru_scan3(const float* __restrict__ WhhT_f, const float* __restrict__ bhh_f,
               const float* __restrict__ WhhT_b, const float* __restrict__ bhh_b,
               const float* __restrict__ h0, float* __restrict__ gi_f,
               float* __restrict__ gi_b)
{
    const int bid  = blockIdx.x;
    const int xcd  = bid & 7;
    const int dir  = (xcd >= 4) ? 1 : 0;
    const int rank = (bid >> 3) * 4 + (xcd & 3);   // 0..127, bijective per dir
    const int m0   = rank * 2;
    const float* WhhT = dir ? WhhT_b : WhhT_f;
    const float* bhh  = dir ? bhh_b  : bhh_f;
    float*       gi   = dir ? gi_b   : gi_f;
    const int tid = threadIdx.x;

    __shared__ float hs[2][304];
    __shared__ float ghs[2][H3];

    float bb = (tid < H3) ? bhh[tid] : 0.0f;

    for (int i = tid; i < 150; i += 1024) {
        int mm = i / 75, q = (i - mm * 75) * 4;
        *(float4*)&hs[mm][q] = *(const float4*)&h0[(long)(m0 + mm) * HH + q];
    }
    __syncthreads();

    for (int s = 0; s < LATM; ++s) {
        const int t = dir ? (LATM - 1 - s) : s;

        // phase 1: gh for all 900 gate units (2 mols)
        if (tid < H3) {
            float a0 = 0.0f, a1 = 0.0f;
            const float* wh = WhhT + tid;
#pragma unroll 4
            for (int k0 = 0; k0 < HH; k0 += 4) {
                float w0 = wh[(long)(k0 + 0) * H3];
                float w1 = wh[(long)(k0 + 1) * H3];
                float w2 = wh[(long)(k0 + 2) * H3];
                float w3 = wh[(long)(k0 + 3) * H3];
                float4 h0v = *(const float4*)&hs[0][k0];
                float4 h1v = *(const float4*)&hs[1][k0];
                a0 += h0v.x * w0 + h0v.y * w1 + h0v.z * w2 + h0v.w * w3;
                a1 += h1v.x * w0 + h1v.y * w1 + h1v.z * w2 + h1v.w * w3;
            }
            ghs[0][tid] = a0 + bb;
            ghs[1][tid] = a1 + bb;
        }
        __syncthreads();

        // phase 2: gates, state update, in-place gout
        if (tid < 2 * HH) {
            int mm = tid / HH, hh = tid - mm * HH;
            long row = (long)(m0 + mm) * LATM + t;
            float* g = gi + row * H3;
            float ir = g[hh], iz = g[HH + hh], inn = g[2 * HH + hh];
            float r  = sigm(ir + ghs[mm][hh]);
            float z  = sigm(iz + ghs[mm][HH + hh]);
            float nn = tanhf(inn + r * ghs[mm][2 * HH + hh]);
            float hn = (1.0f - z) * nn + z * hs[mm][hh];
            hs[mm][hh] = hn;
            g[hh] = hn;
        }
        __syncthreads();
    }
}

__global__ void mean_kernel(const float* __restrict__ ah, float* __restrict__ out)
{
    int idx = blockIdx.x * blockDim.x + threadIdx.x;
    if (idx >= MMOL * HH) return;
    int m = idx / HH;
    int j = idx - m * HH;
    long base = (long)m * LATM * HH + j;
    float s = 0.0f;
    for (int t = 0; t < LATM; ++t) s += ah[base + (long)t * HH];
    out[idx] = s * (1.0f / LATM);
}

// ---------------------------------------------------------------------------
static inline int cdiv(long a, long b) { return (int)((a + b - 1) / b); }

extern "C" void kernel_launch(void* const* d_in, const int* in_sizes, int n_in,
                              void* d_out, int out_size, void* d_ws, size_t ws_size,
                              hipStream_t stream)
{
    const float* f_atoms  = (const float*)d_in[0];
    const float* f_bonds  = (const float*)d_in[1];
    const int*   a2b      = (const int*)d_in[2];
    const int*   b2a      = (const int*)d_in[3];
    const int*   b2revb   = (const int*)d_in[4];
    const float* W_i_atom = (const float*)d_in[5];
    const float* W_i_bond = (const float*)d_in[6];
    const float* W_h0     = (const float*)d_in[7];
    const float* W_h1     = (const float*)d_in[8];
    const float* W_lr     = (const float*)d_in[9];
    const float* gru_bias = (const float*)d_in[10];
    const float* Wih_f    = (const float*)d_in[11];
    const float* Whh_f    = (const float*)d_in[12];
    const float* bih_f    = (const float*)d_in[13];
    const float* bhh_f    = (const float*)d_in[14];
    const float* Wih_b    = (const float*)d_in[15];
    const float* Whh_b    = (const float*)d_in[16];
    const float* bih_b    = (const float*)d_in[17];
    const float* bhh_b    = (const float*)d_in[18];
    const float* W_o      = (const float*)d_in[19];
    const float* b_o      = (const float*)d_in[20];
    float* out = (float*)d_out;

    // fp32 arena (total 295,530,016 <= proven ws floor).
    // Depth-loop regions (as round 5): P@0, S@157287600, MA@235931408,
    // TH@275254208, HFB@294915616.
    // Scan-phase overlays: gi_f@0 (118MB), gi_b@117964800 (ends 235929600),
    // msgx@MA, atomhid@MA, h0+WhhT_f/b in TH, WT depth scratch @HFB.
    const size_t NEED = 295530016;
    if (ws_size < NEED) return;

    char* b = (char*)d_ws;
    float* P   = (float*)b;
    float* S   = (float*)(b + 157287600);
    float* MA  = (float*)(b + 235931408);
    float* TH  = (float*)(b + 275254208);
    float* HFB = (float*)(b + 294915616);

    float* Pia  = P + (size_t)AA * HH;        // ia_rc [A,300]
    float* WT   = HFB;                        // depth-loop 300x300 transpose
    float* giF  = (float*)b;                  // [ML,900]
    float* giB  = (float*)(b + 117964800);    // [ML,900]
    float* MSGX = MA;                         // [ML,300] (MA dead post-node)
    float* AH   = MA;                         // atomhid [ML,300] (msgx dead post-gi)
    float* H0   = TH;                         // [M,300]
    float* WhhT_f = TH + 76800;               // 270,000 floats
    float* WhhT_b = TH + 346800;              // 270,000 floats

    dim3 blk(256);
    const int gA = cdiv((long)AA * HH, 256);
    dim3 gmA (cdiv(AA, 128),   cdiv(HH, 64));
    dim3 gmB3(cdiv(BBND, 128), cdiv(HH, 64));
    dim3 gmB1(cdiv(BBND, 128), cdiv(150, 64));
    dim3 gmT (cdiv(AA, 128),   cdiv(150, 64));
    dim3 gmG (cdiv(MLR, 128),  cdiv(H3, 64));
    dim3 gmO (cdiv(MLR, 128),  cdiv(HH, 64));

    // 1. ma = input_atom ; 2. mb0 = input_bond -> P
    gemm_big<true, false, false><<<gmA, blk, 0, stream>>>(
        f_atoms, AFD, W_i_atom, AFD, nullptr, MA, AA, HH, AFD);
    gemm_big<true, false, false><<<gmB3, blk, 0, stream>>>(
        f_bonds, BFD, W_i_bond, BFD, nullptr, P, BBND, HH, BFD);

    // Depth loop
    const float* Wh[2] = { W_h0, W_h1 };
    for (int d = 0; d < 2; ++d) {
        const float* W = Wh[d];
        aggregate<true><<<gA, blk, 0, stream>>>(P, a2b, MA);
        transpose_kernel<<<cdiv(90000, 256), blk, 0, stream>>>(W, WT, 300, 300);
        gemm_big<false, false, false><<<gmB1, blk, 0, stream>>>(
            P, HH, W, HH, nullptr, S, BBND, 150, HH);
        vw_hi_inplace<<<cdiv(BBND, 16), blk, 0, stream>>>(P, WT, BBND);
        gemm_big<false, false, false><<<gmT, blk, 0, stream>>>(
            MA, HH, W + 150 * HH, HH, nullptr, TH, AA, 150, HH);
        bond_half<<<gmB1, blk, 0, stream>>>(
            f_bonds, W_i_bond, TH, P, 300, b2a, b2revb, P, 150, BBND);
        gemm_big<false, false, false><<<gmT, blk, 0, stream>>>(
            MA, HH, W, HH, nullptr, TH, AA, 150, HH);
        bond_half<<<gmB1, blk, 0, stream>>>(
            f_bonds, W_i_bond, TH, S, 150, b2a, b2revb, P, 0, BBND);
    }

    // Final aggregation -> S
    aggregate<false><<<gA, blk, 0, stream>>>(P, a2b, S);

    // ia recomputed -> Pia ; node -> P[0:A*300)
    gemm_big<true, false, false><<<gmA, blk, 0, stream>>>(
        f_atoms, AFD, W_i_atom, AFD, nullptr, Pia, AA, HH, AFD);
    gemm_big<false, false, false><<<gmA, blk, 0, stream>>>(
        S,   HH, W_lr,          H3, nullptr, P, AA, HH, HH);
    gemm_big<false, false, true><<<gmA, blk, 0, stream>>>(
        MA,  HH, W_lr + HH,     H3, nullptr, P, AA, HH, HH);
    gemm_big<false, false, true><<<gmA, blk, 0, stream>>>(
        Pia, HH, W_lr + 2 * HH, H3, nullptr, P, AA, HH, HH);

    // GRU prep: msgx -> MA region, h0 -> TH, WhhT transposes -> TH
    msgx_kernel<<<cdiv((long)MLR * HH, 256), blk, 0, stream>>>(P, gru_bias, MSGX);
    h0_kernel<<<cdiv(MMOL * HH, 256), blk, 0, stream>>>(P, H0);
    transpose_kernel<<<cdiv(270000, 256), blk, 0, stream>>>(Whh_f, WhhT_f, H3, HH);
    transpose_kernel<<<cdiv(270000, 256), blk, 0, stream>>>(Whh_b, WhhT_b, H3, HH);

    // gi = msgx @ Wih^T + bih (both dirs; overwrites node/mb/agg — all dead)
    gemm_big<false, true, false><<<gmG, blk, 0, stream>>>(
        MSGX, HH, Wih_f, HH, bih_f, giF, MLR, H3, HH);
    gemm_big<false, true, false><<<gmG, blk, 0, stream>>>(
        MSGX, HH, Wih_b, HH, bih_b, giB, MLR, H3, HH);

    // Fused bidirectional scan (gout in-place into gi[t][0:300])
    gru_scan3<<<dim3(256), dim3(1024), 0, stream>>>(
        WhhT_f, bhh_f, WhhT_b, bhh_b, H0, giF, giB);

    // atom_hiddens = relu(gout_f@Wo_lo^T + gout_b@Wo_hi^T + b_o) -> AH (msgx dead)
    gemm_big<false, false, false><<<gmO, blk, 0, stream>>>(
        giF, H3, W_o,      2 * HH, nullptr, AH, MLR, HH, HH);
    gemm_big<true, true, true><<<gmO, blk, 0, stream>>>(
        giB, H3, W_o + HH, 2 * HH, b_o,     AH, MLR, HH, HH);

    // mol_vecs -> out
    mean_kernel<<<cdiv(MMOL * HH, 256), blk, 0, stream>>>(AH, out);
}